// Round 2
// baseline (860.488 us; speedup 1.0000x reference)
//
#include <hip/hip_runtime.h>
#include <hip/hip_bf16.h>

// Problem dims (fixed)
#define BB 2
#define LL 32
#define EE 256
#define HH 4096
#define GG 16
#define RR 64

typedef __bf16 bf16x8 __attribute__((ext_vector_type(8)));
typedef float f32x4 __attribute__((ext_vector_type(4)));

__device__ inline bf16x8 cvt_frag(const float* __restrict__ p) {
    f32x4 a = *(const f32x4*)p;
    f32x4 b = *(const f32x4*)(p + 4);
    bf16x8 r;
    r[0] = (__bf16)a[0]; r[1] = (__bf16)a[1]; r[2] = (__bf16)a[2]; r[3] = (__bf16)a[3];
    r[4] = (__bf16)b[0]; r[5] = (__bf16)b[1]; r[6] = (__bf16)b[2]; r[7] = (__bf16)b[3];
    return r;
}

// ---------------------------------------------------------------------------
// Pass 1: kpart[b,l,e,r] = sum_h K[b,l,e,h]*Wk[r,h]  (and vpart with Wv).
// fp32 inputs, cvt->bf16 in-register, MFMA 16x16x32 bf16 w/ fp32 accum.
// Block = 256 thr (4 waves); each wave covers H/4; LDS cross-wave reduce.
// A frag: A[m=lane&15][k=quad*8+j], B frag: B[k=quad*8+j][n=lane&15]
// C/D: col(n=r)=lane&15, row(m=e)=quad*4+reg
// ---------------------------------------------------------------------------
__global__ __launch_bounds__(256) void proj_kernel(
    const float* __restrict__ ek, const float* __restrict__ ev,
    const float* __restrict__ Wk, const float* __restrict__ Wv,
    __hip_bfloat16* __restrict__ kpart, __hip_bfloat16* __restrict__ vpart)
{
    __shared__ float lds[4][1024];
    const int blk   = blockIdx.x;        // 0..1023
    const int etile = blk & 15;
    const int bl    = blk >> 4;          // b*LL + l
    const int t     = threadIdx.x;
    const int lane  = t & 63;
    const int wave  = t >> 6;
    const int m     = lane & 15;
    const int quad  = lane >> 4;
    const int hbase = wave * (HH / 4) + quad * 8;

    const float* arow_k = ek + ((size_t)bl * EE + etile * 16 + m) * HH + hbase;
    const float* arow_v = ev + ((size_t)bl * EE + etile * 16 + m) * HH + hbase;
    const float* bk0    = Wk + (size_t)m * HH + hbase;
    const float* bv0    = Wv + (size_t)m * HH + hbase;

    f32x4 acck[4] = {};
    f32x4 accv[4] = {};

    for (int h0 = 0; h0 < HH / 4; h0 += 32) {
        bf16x8 ak = cvt_frag(arow_k + h0);
        bf16x8 av = cvt_frag(arow_v + h0);
#pragma unroll
        for (int nt = 0; nt < 4; nt++) {
            bf16x8 bk = cvt_frag(bk0 + (size_t)nt * 16 * HH + h0);
            bf16x8 bv = cvt_frag(bv0 + (size_t)nt * 16 * HH + h0);
            acck[nt] = __builtin_amdgcn_mfma_f32_16x16x32_bf16(ak, bk, acck[nt], 0, 0, 0);
            accv[nt] = __builtin_amdgcn_mfma_f32_16x16x32_bf16(av, bv, accv[nt], 0, 0, 0);
        }
    }

    // cross-wave reduce K
#pragma unroll
    for (int nt = 0; nt < 4; nt++)
#pragma unroll
        for (int reg = 0; reg < 4; reg++)
            lds[wave][nt * 256 + reg * 64 + lane] = acck[nt][reg];
    __syncthreads();
    float ksum[4];
#pragma unroll
    for (int j = 0; j < 4; j++) {
        const int i = t + 256 * j;
        ksum[j] = lds[0][i] + lds[1][i] + lds[2][i] + lds[3][i];
    }
    __syncthreads();
    // cross-wave reduce V
#pragma unroll
    for (int nt = 0; nt < 4; nt++)
#pragma unroll
        for (int reg = 0; reg < 4; reg++)
            lds[wave][nt * 256 + reg * 64 + lane] = accv[nt][reg];
    __syncthreads();

    const size_t ebase = (size_t)bl * EE + etile * 16;
#pragma unroll
    for (int j = 0; j < 4; j++) {
        const int i = t + 256 * j;
        const float vsum = lds[0][i] + lds[1][i] + lds[2][i] + lds[3][i];
        const int nt  = i >> 8;
        const int reg = (i >> 6) & 3;
        const int ln  = i & 63;
        const int er  = (ln >> 4) * 4 + reg;   // e row within tile
        const int r   = nt * 16 + (ln & 15);   // r column
        kpart[(ebase + er) * RR + r] = __float2bfloat16(ksum[j]);
        vpart[(ebase + er) * RR + r] = __float2bfloat16(vsum);
    }
}

// ---------------------------------------------------------------------------
// Pass 2a: raw layer score per (b,l): (1/(E*8)) * sum_{e,r} kpart*lq[r]
// ---------------------------------------------------------------------------
__global__ __launch_bounds__(256) void score_kernel(
    const __hip_bfloat16* __restrict__ kpart, const float* __restrict__ lq,
    float* __restrict__ scores)
{
    const int bl = blockIdx.x;
    const int t  = threadIdx.x;
    __shared__ float red[256];
    __shared__ float lqs[RR];
    if (t < RR) lqs[t] = lq[t];
    __syncthreads();

    const __hip_bfloat16* base = kpart + (size_t)bl * EE * RR;
    float s = 0.f;
#pragma unroll
    for (int j = 0; j < 8; j++) {
        const int i0 = (t + 256 * j) * 8;      // 8 contiguous, same 64-block
        bf16x8 v = *(const bf16x8*)(base + i0);
#pragma unroll
        for (int k = 0; k < 8; k++) s += (float)v[k] * lqs[(i0 + k) & 63];
    }
    red[t] = s; __syncthreads();
    for (int off = 128; off > 0; off >>= 1) {
        if (t < off) red[t] += red[t + off];
        __syncthreads();
    }
    if (t == 0) scores[bl] = red[0] * (1.0f / 2048.0f);
}

// ---------------------------------------------------------------------------
// Pass 2b: softmax over L per b (tiny).
// ---------------------------------------------------------------------------
__global__ __launch_bounds__(64) void softmax_kernel(
    const float* __restrict__ scores, float* __restrict__ layer_w)
{
    const int t = threadIdx.x;
    if (t < BB) {
        const float* s = scores + t * LL;
        float mx = -1e30f;
        for (int l = 0; l < LL; l++) mx = fmaxf(mx, s[l]);
        float e[LL]; float sum = 0.f;
        for (int l = 0; l < LL; l++) { e[l] = __expf(s[l] - mx); sum += e[l]; }
        const float inv = 1.0f / sum;
        for (int l = 0; l < LL; l++) layer_w[t * LL + l] = e[l] * inv;
    }
}

// ---------------------------------------------------------------------------
// Pass 3: kber[b,e,r] = sum_l w[b,l]*kpart[b,l,e,r]  (and vber)
// ---------------------------------------------------------------------------
__global__ __launch_bounds__(64) void kber_kernel(
    const __hip_bfloat16* __restrict__ kpart, const __hip_bfloat16* __restrict__ vpart,
    const float* __restrict__ layer_w,
    float* __restrict__ kber, float* __restrict__ vber)
{
    const int be = blockIdx.x;            // b*EE + e
    const int b  = be >> 8;
    const int e  = be & 255;
    const int r  = threadIdx.x;
    float sk = 0.f, sv = 0.f;
    for (int l = 0; l < LL; l++) {
        const float w = layer_w[b * LL + l];
        const size_t idx = ((size_t)(b * LL + l) * EE + e) * RR + r;
        sk += w * (float)kpart[idx];
        sv += w * (float)vpart[idx];
    }
    kber[(size_t)be * RR + r] = sk;
    vber[(size_t)be * RR + r] = sv;
}

// ---------------------------------------------------------------------------
// Pass 4: q[g,r] = sum_h global_q[g,h] * Wq[r,h]   (fp32)
// ---------------------------------------------------------------------------
__global__ __launch_bounds__(64) void qproj_kernel(
    const float* __restrict__ gq, const float* __restrict__ Wq,
    float* __restrict__ q)
{
    const int g = blockIdx.x;
    const int r = threadIdx.x;
    const float* ga = gq + (size_t)g * HH;
    const float* wa = Wq + (size_t)r * HH;
    float s = 0.f;
    for (int h = 0; h < HH; h += 4) {
        f32x4 a = *(const f32x4*)(ga + h);
        f32x4 w = *(const f32x4*)(wa + h);
        s += a[0]*w[0] + a[1]*w[1] + a[2]*w[2] + a[3]*w[3];
    }
    q[g * RR + r] = s;
}

// ---------------------------------------------------------------------------
// Pass 5: cross attention + mean over g + gated state update + norm clamp.
// ---------------------------------------------------------------------------
__global__ __launch_bounds__(256) void final_kernel(
    const float* __restrict__ q, const float* __restrict__ kber,
    const float* __restrict__ vber, const float* __restrict__ state,
    const int* __restrict__ tokens, float* __restrict__ out)
{
    const int b = blockIdx.x;
    const int t = threadIdx.x;
    __shared__ float qs[GG * RR];
    __shared__ float red[256];
    __shared__ float p[EE];
    __shared__ float ctxp[4][RR];
    __shared__ float sacc[RR];
    __shared__ float prevs[RR], news[RR], upd[RR];
    __shared__ float gate_s, scale_s;

    for (int i = t; i < GG * RR; i += 256) qs[i] = q[i];
    if (t < RR) sacc[t] = 0.f;
    __syncthreads();

    const float* kb = kber + (size_t)b * EE * RR;
    const float* vb = vber + (size_t)b * EE * RR;

    for (int g = 0; g < GG; g++) {
        float s = 0.f;
        const float* krow = kb + t * RR;
#pragma unroll 8
        for (int r = 0; r < RR; r++) s += qs[g * RR + r] * krow[r];
        s *= 0.125f;
        red[t] = s; __syncthreads();
        for (int off = 128; off > 0; off >>= 1) {
            if (t < off) red[t] = fmaxf(red[t], red[t + off]);
            __syncthreads();
        }
        const float mx = red[0];
        __syncthreads();
        const float ex = __expf(s - mx);
        red[t] = ex; __syncthreads();
        for (int off = 128; off > 0; off >>= 1) {
            if (t < off) red[t] += red[t + off];
            __syncthreads();
        }
        const float inv = 1.0f / red[0];
        __syncthreads();
        p[t] = ex * inv;
        __syncthreads();
        const int r = t & 63;
        const int chunk = t >> 6;
        float c = 0.f;
        for (int e = chunk * 64; e < chunk * 64 + 64; e++) c += p[e] * vb[(size_t)e * RR + r];
        ctxp[chunk][r] = c;
        __syncthreads();
        if (t < RR) sacc[t] += (ctxp[0][t] + ctxp[1][t] + ctxp[2][t] + ctxp[3][t]) * (1.0f / GG);
        __syncthreads();
    }

    if (t < RR) { prevs[t] = state[b * RR + t]; news[t] = sacc[t]; }
    __syncthreads();
    if (t == 0) {
        float np = 0.f, ns = 0.f, dp = 0.f;
        for (int r = 0; r < RR; r++) {
            np += prevs[r] * prevs[r];
            ns += news[r] * news[r];
            dp += prevs[r] * news[r];
        }
        np = sqrtf(np); ns = sqrtf(ns);
        float sim = dp / (fmaxf(np, 1e-6f) * fmaxf(ns, 1e-6f));
        sim = fminf(1.0f, fmaxf(-1.0f, sim));
        float gate = 0.1f + 0.8f * 0.5f * (sim + 1.0f);
        // robust scalar read: int or float bit pattern
        const int tv = tokens[0];
        float tokf;
        if (tv >= 0 && tv < (1 << 24)) tokf = (float)tv;
        else tokf = __int_as_float(tv);
        const float evidence = fminf(1.0f, tokf * (1.0f / 256.0f));
        gate_s = gate * evidence;
    }
    __syncthreads();
    const float gate = gate_s;
    if (t < RR) upd[t] = (1.0f - gate) * prevs[t] + gate * news[t];
    __syncthreads();
    if (t == 0) {
        float n = 0.f;
        for (int r = 0; r < RR; r++) n += upd[r] * upd[r];
        n = sqrtf(n);
        scale_s = fminf(1.0f, 10.0f / fmaxf(n, 1e-6f));
    }
    __syncthreads();
    if (t < RR) out[b * RR + t] = upd[t] * scale_s;
}

// ---------------------------------------------------------------------------
extern "C" void kernel_launch(void* const* d_in, const int* in_sizes, int n_in,
                              void* d_out, int out_size, void* d_ws, size_t ws_size,
                              hipStream_t stream) {
    const float* state = (const float*)d_in[0];
    const float* ek    = (const float*)d_in[1];
    const float* ev    = (const float*)d_in[2];
    const float* Wq    = (const float*)d_in[3];
    const float* Wk    = (const float*)d_in[4];
    const float* Wv    = (const float*)d_in[5];
    const float* gq    = (const float*)d_in[6];
    const float* lq    = (const float*)d_in[7];
    const int*   tok   = (const int*)d_in[8];
    float* out = (float*)d_out;

    // workspace layout
    const size_t n_part = (size_t)BB * LL * EE * RR;       // 1,048,576 elements
    __hip_bfloat16* kpart = (__hip_bfloat16*)d_ws;          // 2 MB
    __hip_bfloat16* vpart = kpart + n_part;                 // 2 MB
    float* fr      = (float*)(vpart + n_part);              // fp32 region @4MB
    float* scores  = fr;                                    // 64
    float* layer_w = scores + BB * LL;                      // 64
    float* kber    = layer_w + BB * LL;                     // 128 KB
    float* vber    = kber + (size_t)BB * EE * RR;           // 128 KB
    float* qbuf    = vber + (size_t)BB * EE * RR;           // 4 KB

    proj_kernel<<<BB * LL * (EE / 16), 256, 0, stream>>>(ek, ev, Wk, Wv, kpart, vpart);
    score_kernel<<<BB * LL, 256, 0, stream>>>(kpart, lq, scores);
    softmax_kernel<<<1, 64, 0, stream>>>(scores, layer_w);
    kber_kernel<<<BB * EE, 64, 0, stream>>>(kpart, vpart, layer_w, kber, vber);
    qproj_kernel<<<GG, 64, 0, stream>>>(gq, Wq, qbuf);
    final_kernel<<<BB, 256, 0, stream>>>(qbuf, kber, vber, state, tok, out);
}

// Round 3
// 625.707 us; speedup vs baseline: 1.3752x; 1.3752x over previous
//
#include <hip/hip_runtime.h>
#include <hip/hip_bf16.h>
#include <stdint.h>

// Problem dims (fixed)
#define BB 2
#define LL 32
#define EE 256
#define HH 4096
#define GG 16
#define RR 64

typedef __bf16 bf16x8 __attribute__((ext_vector_type(8)));
typedef float f32x4 __attribute__((ext_vector_type(4)));

__device__ inline void async16(const void* g, void* l) {
    __builtin_amdgcn_global_load_lds((const __attribute__((address_space(1))) uint32_t*)g,
                                     (__attribute__((address_space(3))) uint32_t*)l, 16, 0, 0);
}

__device__ inline bf16x8 cvt8(f32x4 a, f32x4 b) {
    bf16x8 r;
    r[0] = (__bf16)a[0]; r[1] = (__bf16)a[1]; r[2] = (__bf16)a[2]; r[3] = (__bf16)a[3];
    r[4] = (__bf16)b[0]; r[5] = (__bf16)b[1]; r[6] = (__bf16)b[2]; r[7] = (__bf16)b[3];
    return r;
}

// ---------------------------------------------------------------------------
// Prep: pre-swizzle Wk/Wv (fp32 [64][4096]) into frag-native bf16 layout:
//   Bfrag[mat][kq(512)][r(64)][j(8)] = W[r][kq*8+j]
// Also zero the scores accumulator.
// ---------------------------------------------------------------------------
__global__ __launch_bounds__(256) void prep_kernel(
    const float* __restrict__ Wk, const float* __restrict__ Wv,
    __hip_bfloat16* __restrict__ Bfrag, float* __restrict__ scores)
{
    const int tid = blockIdx.x * 256 + threadIdx.x;   // 65536 tasks
    const int mat = tid >> 15;
    const int r   = (tid >> 9) & 63;
    const int kq  = tid & 511;
    const float* W = mat ? Wv : Wk;
    const float* src = W + (size_t)r * HH + kq * 8;
    f32x4 a = *(const f32x4*)src;
    f32x4 b = *(const f32x4*)(src + 4);
    bf16x8 o = cvt8(a, b);
    *(bf16x8*)((__bf16*)Bfrag + ((size_t)(mat * 512 + kq) * 64 + r) * 8) = o;
    if (blockIdx.x == 0 && threadIdx.x < BB * LL) scores[threadIdx.x] = 0.f;
}

// ---------------------------------------------------------------------------
// Proj: kpart[b,l,e,r] = sum_h K[b,l,e,h]*Wk[r,h]  (vpart with Wv), MFMA.
// Grid 512 = 64 bl x 8 etiles(32 rows). 4 waves: wave = (mat, mtile).
// K-chunk = 128 h. LDS: A row-major (pair-padded), B frag-native.
// Fused: layer-score partial  sum_{e,r} kout*lq[r]  -> atomicAdd(scores[bl]).
// ---------------------------------------------------------------------------
__global__ __launch_bounds__(256) void proj_kernel(
    const float* __restrict__ ek, const float* __restrict__ ev,
    const __hip_bfloat16* __restrict__ Bfrag, const float* __restrict__ lq,
    __hip_bfloat16* __restrict__ kpart, __hip_bfloat16* __restrict__ vpart,
    float* __restrict__ scores)
{
    // LDS layout (bytes):
    //  A_K: [16 rowpairs][1056]   0 .. 16896      (pair = 2 rows x 512B + 32B pad)
    //  A_V: 16896 .. 33792
    //  B_K: [16 kq][64 lanes][16B]  33792 .. 50176
    //  B_V: 50176 .. 66560
    __shared__ __align__(16) float smem[16640];
    uint8_t* sm = (uint8_t*)smem;

    const int blk  = blockIdx.x;
    const int bl   = blk >> 3;
    const int e0   = (blk & 7) * 32;
    const int t    = threadIdx.x;
    const int w    = t >> 6;
    const int lane = t & 63;
    const int n    = lane & 15;
    const int quad = lane >> 4;

    const int mat = w >> 1;    // compute role: 0=K 1=V
    const int mt  = w & 1;     // m-tile (rows mt*16..mt*16+15)

    f32x4 acc[4] = {};
    const size_t rowbase = (size_t)bl * EE + e0;

    // per-wave staging pointers (wave 0: A_K, 1: A_V, 2: B_K, 3: B_V)
    const float* asrc = (w == 0) ? ek : ev;
    const float* agp0 = asrc + (rowbase + (lane >> 5)) * (size_t)HH + (lane & 31) * 4;
    const __hip_bfloat16* bsrc = Bfrag + (size_t)(w & 1) * 512 * 64 * 8;
    uint8_t* adst = sm + w * 16896;            // valid for w<2
    uint8_t* bdst = sm + 33792 + (w & 1) * 16384;

    const uint8_t* abase = sm + mat * 16896;
    const uint8_t* bbase = sm + 33792 + mat * 16384;
    const int m = mt * 16 + n;
    const uint8_t* arow = abase + (m >> 1) * 1056 + (m & 1) * 512;

    for (int c = 0; c < 32; c++) {
        const int h0 = c * 128;
        if (w < 2) {
            const float* gp = agp0 + h0;
#pragma unroll
            for (int p = 0; p < 16; p++)
                async16(gp + (size_t)2 * p * HH, adst + p * 1056);
        } else {
            const __hip_bfloat16* gp = bsrc + ((size_t)(c * 16) * 64 + lane) * 8;
#pragma unroll
            for (int kq = 0; kq < 16; kq++)
                async16(gp + (size_t)kq * 64 * 8, bdst + kq * 1024);
        }
        __syncthreads();
#pragma unroll
        for (int kc = 0; kc < 4; kc++) {
            const float* ap = (const float*)(arow + (kc * 32 + quad * 8) * 4);
            f32x4 a0 = *(const f32x4*)ap;
            f32x4 a1 = *(const f32x4*)(ap + 4);
            bf16x8 af = cvt8(a0, a1);
#pragma unroll
            for (int nt = 0; nt < 4; nt++) {
                bf16x8 bfv = *(const bf16x8*)(bbase + (size_t)((kc * 4 + quad) * 64 + nt * 16 + n) * 16);
                acc[nt] = __builtin_amdgcn_mfma_f32_16x16x32_bf16(af, bfv, acc[nt], 0, 0, 0);
            }
        }
        __syncthreads();
    }

    // epilogue: store outputs (C/D layout: col=n, row=quad*4+reg), fused score
    __hip_bfloat16* outp = (mat == 0) ? kpart : vpart;
    float lqv[4];
    if (mat == 0) {
#pragma unroll
        for (int nt = 0; nt < 4; nt++) lqv[nt] = lq[nt * 16 + n];
    }
    float sc = 0.f;
#pragma unroll
    for (int nt = 0; nt < 4; nt++)
#pragma unroll
        for (int reg = 0; reg < 4; reg++) {
            const int e_row = e0 + mt * 16 + quad * 4 + reg;
            outp[((size_t)bl * EE + e_row) * RR + nt * 16 + n] = __float2bfloat16(acc[nt][reg]);
            if (mat == 0) sc += acc[nt][reg] * lqv[nt];
        }
    if (mat == 0) {
#pragma unroll
        for (int off = 32; off > 0; off >>= 1) sc += __shfl_down(sc, off, 64);
        if (lane == 0) atomicAdd(&scores[bl], sc);
    }
}

// ---------------------------------------------------------------------------
// kber: softmax(scores) inline; kberT[b][r][e] = sum_l w_l * kpart[b,l,e,r]
// Grid 16 = 2 b x 8 eblocks(32). Coalesced bf16x8 loads.
// ---------------------------------------------------------------------------
__global__ __launch_bounds__(256) void kber_kernel(
    const __hip_bfloat16* __restrict__ kpart, const __hip_bfloat16* __restrict__ vpart,
    const float* __restrict__ scores,
    float* __restrict__ kberT, float* __restrict__ vberT)
{
    const int blk = blockIdx.x;
    const int b   = blk >> 3;
    const int e0  = (blk & 7) * 32;
    const int t   = threadIdx.x;
    __shared__ float wl[LL];
    if (t == 0) {
        float s[LL]; float mx = -1e30f;
        for (int l = 0; l < LL; l++) { s[l] = scores[b * LL + l] * (1.f / 2048.f); mx = fmaxf(mx, s[l]); }
        float sum = 0.f;
        for (int l = 0; l < LL; l++) { s[l] = __expf(s[l] - mx); sum += s[l]; }
        const float inv = 1.0f / sum;
        for (int l = 0; l < LL; l++) wl[l] = s[l] * inv;
    }
    __syncthreads();
    const int e_l = t >> 3;
    const int r0  = (t & 7) * 8;
    float sk[8] = {}, sv[8] = {};
    for (int l = 0; l < LL; l++) {
        const float wv_ = wl[l];
        const size_t base = ((size_t)(b * LL + l) * EE + e0 + e_l) * RR + r0;
        bf16x8 k8 = *(const bf16x8*)((const __bf16*)kpart + base);
        bf16x8 v8 = *(const bf16x8*)((const __bf16*)vpart + base);
#pragma unroll
        for (int j = 0; j < 8; j++) { sk[j] += wv_ * (float)k8[j]; sv[j] += wv_ * (float)v8[j]; }
    }
    const int e = e0 + e_l;
#pragma unroll
    for (int j = 0; j < 8; j++) {
        kberT[((size_t)b * RR + r0 + j) * EE + e] = sk[j];
        vberT[((size_t)b * RR + r0 + j) * EE + e] = sv[j];
    }
}

// ---------------------------------------------------------------------------
// qproj: q[g,r] = sum_h gq[g,h]*Wq[r,h].  Grid 64 = 16 g x 4 r-quarters.
// ---------------------------------------------------------------------------
__global__ __launch_bounds__(256) void qproj_kernel(
    const float* __restrict__ gq, const float* __restrict__ Wq,
    float* __restrict__ q)
{
    const int g  = blockIdx.x >> 2;
    const int rq = blockIdx.x & 3;
    const int t  = threadIdx.x;
    __shared__ float red[16][256];
    __shared__ float r2[16][17];
    float s[16] = {};
    for (int i = 0; i < 4; i++) {
        const int h = i * 1024 + t * 4;
        f32x4 a = *(const f32x4*)(gq + (size_t)g * HH + h);
#pragma unroll
        for (int r = 0; r < 16; r++) {
            f32x4 wv_ = *(const f32x4*)(Wq + (size_t)(rq * 16 + r) * HH + h);
            s[r] += a[0] * wv_[0] + a[1] * wv_[1] + a[2] * wv_[2] + a[3] * wv_[3];
        }
    }
#pragma unroll
    for (int r = 0; r < 16; r++) red[r][t] = s[r];
    __syncthreads();
    {
        const int r = t >> 4, j = t & 15;
        float p = 0.f;
        for (int i = 0; i < 16; i++) p += red[r][j * 16 + i];
        r2[r][j] = p;
    }
    __syncthreads();
    if (t < 16) {
        float p = 0.f;
        for (int j = 0; j < 16; j++) p += r2[t][j];
        q[g * RR + rq * 16 + t] = p;
    }
}

// ---------------------------------------------------------------------------
// Final: cross attention (kberT/vberT transposed layouts) + gate + clamp.
// ---------------------------------------------------------------------------
__global__ __launch_bounds__(256) void final_kernel(
    const float* __restrict__ q, const float* __restrict__ kberT,
    const float* __restrict__ vberT, const float* __restrict__ state,
    const int* __restrict__ tokens, float* __restrict__ out)
{
    const int b = blockIdx.x;
    const int t = threadIdx.x;
    __shared__ float qs[GG * RR];
    __shared__ float red[256];
    __shared__ float p[EE];
    __shared__ float ctx2[RR][5];
    __shared__ float sacc[RR];
    __shared__ float prevs[RR], news[RR], upd[RR];
    __shared__ float gate_s, scale_s;

    for (int i = t; i < GG * RR; i += 256) qs[i] = q[i];
    if (t < RR) sacc[t] = 0.f;
    __syncthreads();

    const float* kT = kberT + (size_t)b * RR * EE;   // [r][e]
    const float* vT = vberT + (size_t)b * RR * EE;

    for (int g = 0; g < GG; g++) {
        float s = 0.f;
#pragma unroll 8
        for (int r = 0; r < RR; r++) s += qs[g * RR + r] * kT[(size_t)r * EE + t];
        s *= 0.125f;
        red[t] = s; __syncthreads();
        for (int off = 128; off > 0; off >>= 1) {
            if (t < off) red[t] = fmaxf(red[t], red[t + off]);
            __syncthreads();
        }
        const float mx = red[0];
        __syncthreads();
        const float ex = __expf(s - mx);
        red[t] = ex; __syncthreads();
        for (int off = 128; off > 0; off >>= 1) {
            if (t < off) red[t] += red[t + off];
            __syncthreads();
        }
        const float inv = 1.0f / red[0];
        __syncthreads();
        p[t] = ex * inv;
        __syncthreads();
        // context: thread -> (r = t>>2, e-segment = t&3)
        const int r  = t >> 2;
        const int es = t & 3;
        const float* vrow = vT + (size_t)r * EE + es * 64;
        float c = 0.f;
#pragma unroll 4
        for (int i = 0; i < 64; i++) c += p[es * 64 + i] * vrow[i];
        ctx2[r][es] = c;
        __syncthreads();
        if (t < RR) sacc[t] += (ctx2[t][0] + ctx2[t][1] + ctx2[t][2] + ctx2[t][3]) * (1.0f / GG);
        __syncthreads();
    }

    if (t < RR) { prevs[t] = state[b * RR + t]; news[t] = sacc[t]; }
    __syncthreads();
    if (t == 0) {
        float np = 0.f, ns = 0.f, dp = 0.f;
        for (int r = 0; r < RR; r++) {
            np += prevs[r] * prevs[r];
            ns += news[r] * news[r];
            dp += prevs[r] * news[r];
        }
        np = sqrtf(np); ns = sqrtf(ns);
        float sim = dp / (fmaxf(np, 1e-6f) * fmaxf(ns, 1e-6f));
        sim = fminf(1.0f, fmaxf(-1.0f, sim));
        float gate = 0.1f + 0.8f * 0.5f * (sim + 1.0f);
        const int tv = tokens[0];
        float tokf;
        if (tv >= 0 && tv < (1 << 24)) tokf = (float)tv;
        else tokf = __int_as_float(tv);
        const float evidence = fminf(1.0f, tokf * (1.0f / 256.0f));
        gate_s = gate * evidence;
    }
    __syncthreads();
    const float gate = gate_s;
    if (t < RR) upd[t] = (1.0f - gate) * prevs[t] + gate * news[t];
    __syncthreads();
    if (t == 0) {
        float nn = 0.f;
        for (int r = 0; r < RR; r++) nn += upd[r] * upd[r];
        nn = sqrtf(nn);
        scale_s = fminf(1.0f, 10.0f / fmaxf(nn, 1e-6f));
    }
    __syncthreads();
    if (t < RR) out[b * RR + t] = upd[t] * scale_s;
}

// ---------------------------------------------------------------------------
extern "C" void kernel_launch(void* const* d_in, const int* in_sizes, int n_in,
                              void* d_out, int out_size, void* d_ws, size_t ws_size,
                              hipStream_t stream) {
    const float* state = (const float*)d_in[0];
    const float* ek    = (const float*)d_in[1];
    const float* ev    = (const float*)d_in[2];
    const float* Wq    = (const float*)d_in[3];
    const float* Wk    = (const float*)d_in[4];
    const float* Wv    = (const float*)d_in[5];
    const float* gq    = (const float*)d_in[6];
    const float* lq    = (const float*)d_in[7];
    const int*   tok   = (const int*)d_in[8];
    float* out = (float*)d_out;

    // workspace layout
    const size_t n_part = (size_t)BB * LL * EE * RR;     // 1,048,576
    __hip_bfloat16* kpart = (__hip_bfloat16*)d_ws;        // 2 MB
    __hip_bfloat16* vpart = kpart + n_part;               // 2 MB
    __hip_bfloat16* Bfrag = vpart + n_part;               // 1 MB (2*512*64*8)
    float* fr      = (float*)(Bfrag + (size_t)2 * 512 * 64 * 8);
    float* scores  = fr;                                  // 64
    float* kberT   = scores + BB * LL;                    // 128 KB
    float* vberT   = kberT + (size_t)BB * RR * EE;        // 128 KB
    float* qbuf    = vberT + (size_t)BB * RR * EE;        // 4 KB

    prep_kernel<<<256, 256, 0, stream>>>(Wk, Wv, Bfrag, scores);
    proj_kernel<<<512, 256, 0, stream>>>(ek, ev, Bfrag, lq, kpart, vpart, scores);
    kber_kernel<<<16, 256, 0, stream>>>(kpart, vpart, scores, kberT, vberT);
    qproj_kernel<<<64, 256, 0, stream>>>(gq, Wq, qbuf);
    final_kernel<<<BB, 256, 0, stream>>>(qbuf, kberT, vberT, state, tok, out);
}